// Round 1
// baseline (422.476 us; speedup 1.0000x reference)
//
#include <hip/hip_runtime.h>

#define DEV __device__ __forceinline__

typedef _Float16 half8  __attribute__((ext_vector_type(8)));
typedef _Float16 half4h __attribute__((ext_vector_type(4)));
typedef float    f32x4  __attribute__((ext_vector_type(4)));

// Problem constants
static constexpr int Bb = 8;
static constexpr int Ff = 16;
static constexpr int Pp = 196;
static constexpr int Dd = 768;
static constexpr int Hh = 12;
static constexpr int HD = 64;
static constexpr int Nn = 3136;    // F*P tokens per batch
static constexpr int NT = 25088;   // B*N total tokens

#define MFMA(a, b, c) __builtin_amdgcn_mfma_f32_16x16x32_f16(a, b, c, 0, 0, 0)

DEV void gll16(const _Float16* g, _Float16* l) {
  __builtin_amdgcn_global_load_lds(
      (__attribute__((address_space(1))) void*)(g),
      (__attribute__((address_space(3))) void*)(l), 16, 0, 0);
}

// Intra-wave LDS write->read fence: drain all outstanding mem ops, forbid
// compiler motion across it. (Per-wave private LDS buffers; no __syncthreads.)
DEV void wave_fence_lds() {
  __builtin_amdgcn_sched_barrier(0);
  __builtin_amdgcn_s_waitcnt(0);
  __builtin_amdgcn_sched_barrier(0);
}

// ---------------------------------------------------------------- convert
__global__ __launch_bounds__(256) void cvt_f32_f16(const float* __restrict__ s,
                                                   _Float16* __restrict__ d,
                                                   int n4) {
  int i = blockIdx.x * 256 + threadIdx.x;
  if (i >= n4) return;
  f32x4 v = ((const f32x4*)s)[i];
  half4h h;
  h.x = (_Float16)v.x; h.y = (_Float16)v.y;
  h.z = (_Float16)v.z; h.w = (_Float16)v.w;
  ((half4h*)d)[i] = h;
}

// ---------------------------------------------------------------- QKV GEMM
// C[token][e] = sum_d X[token][d] * W[e][d];  M=25088, N=2304, K=768.
// 128x128 tile, BK=32, 4 waves (2x2 of 64x64). Epilogue: LDS round trip.
// Q,K written as (B,H,N,hd) fp16; V written transposed as (B,H,hd,N) fp16.
__global__ __launch_bounds__(256) void gemm_qkv(const _Float16* __restrict__ X,
                                                const _Float16* __restrict__ W,
                                                _Float16* __restrict__ Qb,
                                                _Float16* __restrict__ Kb,
                                                _Float16* __restrict__ Vt) {
  __shared__ __align__(16) _Float16 smem[128 * 128];  // 32 KB (staging + C-tile)
  _Float16* As = smem;             // [128][32]
  _Float16* Bs = smem + 128 * 32;  // [128][32]
  const int tid = threadIdx.x;
  const int lane = tid & 63, wid = tid >> 6;
  const int l15 = lane & 15, quad = lane >> 4;
  const int row0 = blockIdx.y * 128;  // token tile
  const int e0 = blockIdx.x * 128;    // feature tile
  const int wm = (wid >> 1) * 64, wn = (wid & 1) * 64;

  const _Float16* Ag = X + (size_t)row0 * Dd;
  const _Float16* Bg = W + (size_t)e0 * Dd;

  f32x4 acc[4][4];
#pragma unroll
  for (int i = 0; i < 4; ++i)
#pragma unroll
    for (int j = 0; j < 4; ++j) acc[i][j] = (f32x4)0.0f;

  const int c0 = tid, c1 = tid + 256;
  const int r0s = c0 >> 2, o0 = (c0 & 3) * 8;
  const int r1s = c1 >> 2, o1 = (c1 & 3) * 8;

  for (int kt = 0; kt < 24; ++kt) {
    const int k0 = kt * 32;
    __syncthreads();
    gll16(Ag + (size_t)r0s * Dd + k0 + o0, As + c0 * 8);
    gll16(Bg + (size_t)r0s * Dd + k0 + o0, Bs + c0 * 8);
    gll16(Ag + (size_t)r1s * Dd + k0 + o1, As + c1 * 8);
    gll16(Bg + (size_t)r1s * Dd + k0 + o1, Bs + c1 * 8);
    __syncthreads();
    half8 af[4], bf[4];
#pragma unroll
    for (int t = 0; t < 4; ++t) {
      af[t] = *(const half8*)(As + (wm + t * 16 + l15) * 32 + quad * 8);
      bf[t] = *(const half8*)(Bs + (wn + t * 16 + l15) * 32 + quad * 8);
    }
#pragma unroll
    for (int i = 0; i < 4; ++i)
#pragma unroll
      for (int j = 0; j < 4; ++j) acc[i][j] = MFMA(af[i], bf[j], acc[i][j]);
  }

  __syncthreads();
  const int tsel = e0 / Dd;  // 0=Q, 1=K, 2=V (768 = 6*128, never straddles)
  if (tsel == 2) {
    // LDS layout Ct[e_local][tok_local] -> vectorized 8B writes (4 consec tokens)
#pragma unroll
    for (int i = 0; i < 4; ++i)
#pragma unroll
      for (int j = 0; j < 4; ++j) {
        const int m = wm + i * 16 + quad * 4;  // token local (4 consecutive)
        const int n = wn + j * 16 + l15;       // e local
        half4h hv;
        hv.x = (_Float16)acc[i][j].x; hv.y = (_Float16)acc[i][j].y;
        hv.z = (_Float16)acc[i][j].z; hv.w = (_Float16)acc[i][j].w;
        *(half4h*)(smem + n * 128 + m) = hv;
      }
    __syncthreads();
    for (int c = tid; c < 2048; c += 256) {
      const int el = c >> 4;         // e_local
      const int tk = (c & 15) * 8;   // token chunk (8 tokens; 3136%8==0)
      const int e = e0 + el;
      const int h = (e >> 6) % Hh;
      const int d = e & 63;
      const int r = row0 + tk;
      const int b = r / Nn, n = r % Nn;
      *(half8*)(Vt + ((size_t)((b * Hh + h) * HD + d)) * Nn + n) =
          *(const half8*)(smem + el * 128 + tk);
    }
  } else {
    _Float16* Ob = (tsel == 0) ? Qb : Kb;
    // LDS layout C[tok][e] -> read rows for vectorized global stores
#pragma unroll
    for (int i = 0; i < 4; ++i)
#pragma unroll
      for (int j = 0; j < 4; ++j) {
        const int n = wn + j * 16 + l15;
#pragma unroll
        for (int r = 0; r < 4; ++r) {
          const int m = wm + i * 16 + quad * 4 + r;
          smem[m * 128 + n] = (_Float16)acc[i][j][r];
        }
      }
    __syncthreads();
    for (int c = tid; c < 2048; c += 256) {
      const int ml = c >> 4;         // token local
      const int dl = (c & 15) * 8;   // e chunk (8 within one head)
      const int r = row0 + ml;
      const int b = r / Nn, n = r % Nn;
      const int e = e0 + dl;
      const int h = (e >> 6) % Hh;
      const int d = e & 63;
      *(half8*)(Ob + ((size_t)((b * Hh + h) * Nn + n)) * HD + d) =
          *(const half8*)(smem + ml * 128 + dl);
    }
  }
}

// ---------------------------------------------------------------- proj GEMM
// Out[token][e] = sum_d w[token][d] * Wp[e][d] + bias[e]; fp32 output.
__global__ __launch_bounds__(256) void gemm_proj(const _Float16* __restrict__ Wbuf,
                                                 const _Float16* __restrict__ Wp,
                                                 const float* __restrict__ bias,
                                                 float* __restrict__ Out) {
  __shared__ __align__(16) _Float16 smem[128 * 64];  // 16 KB staging
  _Float16* As = smem;
  _Float16* Bs = smem + 128 * 32;
  const int tid = threadIdx.x;
  const int lane = tid & 63, wid = tid >> 6;
  const int l15 = lane & 15, quad = lane >> 4;
  const int row0 = blockIdx.y * 128;
  const int e0 = blockIdx.x * 128;
  const int wm = (wid >> 1) * 64, wn = (wid & 1) * 64;

  const _Float16* Ag = Wbuf + (size_t)row0 * Dd;
  const _Float16* Bg = Wp + (size_t)e0 * Dd;

  f32x4 acc[4][4];
#pragma unroll
  for (int i = 0; i < 4; ++i)
#pragma unroll
    for (int j = 0; j < 4; ++j) acc[i][j] = (f32x4)0.0f;

  const int c0 = tid, c1 = tid + 256;
  const int r0s = c0 >> 2, o0 = (c0 & 3) * 8;
  const int r1s = c1 >> 2, o1 = (c1 & 3) * 8;

  for (int kt = 0; kt < 24; ++kt) {
    const int k0 = kt * 32;
    __syncthreads();
    gll16(Ag + (size_t)r0s * Dd + k0 + o0, As + c0 * 8);
    gll16(Bg + (size_t)r0s * Dd + k0 + o0, Bs + c0 * 8);
    gll16(Ag + (size_t)r1s * Dd + k0 + o1, As + c1 * 8);
    gll16(Bg + (size_t)r1s * Dd + k0 + o1, Bs + c1 * 8);
    __syncthreads();
    half8 af[4], bf[4];
#pragma unroll
    for (int t = 0; t < 4; ++t) {
      af[t] = *(const half8*)(As + (wm + t * 16 + l15) * 32 + quad * 8);
      bf[t] = *(const half8*)(Bs + (wn + t * 16 + l15) * 32 + quad * 8);
    }
#pragma unroll
    for (int i = 0; i < 4; ++i)
#pragma unroll
      for (int j = 0; j < 4; ++j) acc[i][j] = MFMA(af[i], bf[j], acc[i][j]);
  }

#pragma unroll
  for (int j = 0; j < 4; ++j) {
    const int e = e0 + wn + j * 16 + l15;
    const float bj = bias[e];
#pragma unroll
    for (int i = 0; i < 4; ++i) {
      const int rb = row0 + wm + i * 16 + quad * 4;
#pragma unroll
      for (int r = 0; r < 4; ++r)
        Out[(size_t)(rb + r) * Dd + e] = acc[i][j][r] + bj;
    }
  }
}

// ------------------------------------------------------------ spatial attn
// One block per (b, f, h<6); 4 waves; each wave owns 16-query tiles
// qi = wid, wid+4, wid+8, wid+12 (valid qi <= 12; 196 queries padded to 208).
__global__ __launch_bounds__(256) void attn_spatial(const _Float16* __restrict__ Qb,
                                                    const _Float16* __restrict__ Kb,
                                                    const _Float16* __restrict__ Vt,
                                                    _Float16* __restrict__ Wbuf) {
  __shared__ __align__(16) _Float16 Plds[4][16 * 224];  // per-wave P tile, 28 KB
  const int tid = threadIdx.x;
  const int lane = tid & 63, wid = tid >> 6;
  const int l15 = lane & 15, quad = lane >> 4;
  const int gid = blockIdx.x;
  const int h = gid % 6, f = (gid / 6) % Ff, b = gid / 96;
  const size_t bh = (size_t)b * Hh + h;
  const _Float16* Qh = Qb + (bh * Nn + (size_t)f * Pp) * HD;
  const _Float16* Kh = Kb + (bh * Nn + (size_t)f * Pp) * HD;
  const _Float16* Vh = Vt + bh * HD * Nn + (size_t)f * Pp;  // [d][key], stride Nn
  _Float16* Pw = &Plds[wid][0];

  half8 h8z;
#pragma unroll
  for (int z = 0; z < 8; ++z) h8z[z] = (_Float16)0.0f;

  {  // zero pad key-cols 208..223 (cols 196..207 get exp(masked)=0 each tile)
    half4h z4;
    z4.x = z4.y = z4.z = z4.w = (_Float16)0.0f;
    *(half4h*)(Pw + l15 * 224 + 208 + quad * 4) = z4;
  }

  for (int it = 0; it < 4; ++it) {
    const int qi = wid + it * 4;
    if (qi <= 12) {
      const int qr = qi * 16 + l15;
      const int qc = qr < 195 ? qr : 195;  // clamp pad-queries (rows discarded)
      const half8 aq0 = *(const half8*)(Qh + (size_t)qc * HD + quad * 8);
      const half8 aq1 = *(const half8*)(Qh + (size_t)qc * HD + 32 + quad * 8);

      f32x4 s[13];
#pragma unroll
      for (int kt = 0; kt < 13; ++kt) {
        const int krr = kt * 16 + l15;
        const int kc = krr < 195 ? krr : 195;
        const half8 bk0 = *(const half8*)(Kh + (size_t)kc * HD + quad * 8);
        const half8 bk1 = *(const half8*)(Kh + (size_t)kc * HD + 32 + quad * 8);
        f32x4 t = (f32x4)0.0f;
        t = MFMA(aq0, bk0, t);
        t = MFMA(aq1, bk1, t);
        s[kt] = t * 0.125f;  // hd^-0.5
      }
      if (l15 >= 4) s[12] = (f32x4)(-1e30f);  // mask keys 196..207

      f32x4 mx = s[0];
#pragma unroll
      for (int kt = 1; kt < 13; ++kt) {
        mx.x = fmaxf(mx.x, s[kt].x); mx.y = fmaxf(mx.y, s[kt].y);
        mx.z = fmaxf(mx.z, s[kt].z); mx.w = fmaxf(mx.w, s[kt].w);
      }
#pragma unroll
      for (int off = 1; off < 16; off <<= 1) {
        mx.x = fmaxf(mx.x, __shfl_xor(mx.x, off, 16));
        mx.y = fmaxf(mx.y, __shfl_xor(mx.y, off, 16));
        mx.z = fmaxf(mx.z, __shfl_xor(mx.z, off, 16));
        mx.w = fmaxf(mx.w, __shfl_xor(mx.w, off, 16));
      }

      f32x4 sm = (f32x4)0.0f;
#pragma unroll
      for (int kt = 0; kt < 13; ++kt) {
        f32x4 e;
        e.x = __expf(s[kt].x - mx.x); e.y = __expf(s[kt].y - mx.y);
        e.z = __expf(s[kt].z - mx.z); e.w = __expf(s[kt].w - mx.w);
        sm += e;
        const int col = kt * 16 + l15;
        Pw[(quad * 4 + 0) * 224 + col] = (_Float16)e.x;
        Pw[(quad * 4 + 1) * 224 + col] = (_Float16)e.y;
        Pw[(quad * 4 + 2) * 224 + col] = (_Float16)e.z;
        Pw[(quad * 4 + 3) * 224 + col] = (_Float16)e.w;
      }
#pragma unroll
      for (int off = 1; off < 16; off <<= 1) {
        sm.x += __shfl_xor(sm.x, off, 16);
        sm.y += __shfl_xor(sm.y, off, 16);
        sm.z += __shfl_xor(sm.z, off, 16);
        sm.w += __shfl_xor(sm.w, off, 16);
      }
      wave_fence_lds();  // P writes -> A-frag reads (same wave, cross-lane)

      f32x4 o[4];
#pragma unroll
      for (int tj = 0; tj < 4; ++tj) o[tj] = (f32x4)0.0f;
#pragma unroll
      for (int ks = 0; ks < 7; ++ks) {
        const half8 ap = *(const half8*)(Pw + l15 * 224 + ks * 32 + quad * 8);
        const int k0 = ks * 32 + quad * 8;
#pragma unroll
        for (int tj = 0; tj < 4; ++tj) {
          const int d = tj * 16 + l15;
          half8 bv = h8z;
          if (k0 < 196)  // run 192..199 may read next-f data; P=0 there
            bv = *(const half8*)(Vh + (size_t)d * Nn + k0);
          o[tj] = MFMA(ap, bv, o[tj]);
        }
      }
      const float invs[4] = {1.0f / sm.x, 1.0f / sm.y, 1.0f / sm.z, 1.0f / sm.w};
#pragma unroll
      for (int tj = 0; tj < 4; ++tj) {
        const int d = tj * 16 + l15;
#pragma unroll
        for (int r = 0; r < 4; ++r) {
          const int q = qi * 16 + quad * 4 + r;
          if (q < 196)
            Wbuf[(size_t)(b * Nn + f * Pp + q) * Dd + h * HD + d] =
                (_Float16)(o[tj][r] * invs[r]);
        }
      }
      wave_fence_lds();  // PV reads done before next iter's P writes (WAR)
    }
  }
}

// ----------------------------------------------------------- temporal attn
// reshape(B*P,H2,F,hd) == chunks of 16 consecutive tokens within one (b, head)
// for heads 6..11 (group 16 | 3136). One wave per 16x16x64 problem.
__global__ __launch_bounds__(256) void attn_temporal(const _Float16* __restrict__ Qb,
                                                     const _Float16* __restrict__ Kb,
                                                     const _Float16* __restrict__ Vt,
                                                     _Float16* __restrict__ Wbuf) {
  __shared__ __align__(16) _Float16 Plds[4][16 * 32];  // per-wave, 4 KB
  const int tid = threadIdx.x;
  const int lane = tid & 63, wid = tid >> 6;
  const int l15 = lane & 15, quad = lane >> 4;
  const int p = blockIdx.x * 4 + wid;  // [0, 9408)
  const int J0 = p << 4;               // flat row over (B, H2, N)
  const int b = J0 / 18816;            // H2*N = 18816
  const int rem = J0 % 18816;
  const int hh = rem / Nn;             // temporal head (0..5) -> global 6+hh
  const int n0 = rem % Nn;             // 16-aligned token base
  const size_t bh = (size_t)b * Hh + 6 + hh;
  const _Float16* Qh = Qb + (bh * Nn + n0) * HD;
  const _Float16* Kh = Kb + (bh * Nn + n0) * HD;
  const _Float16* Vh = Vt + bh * HD * Nn + n0;
  _Float16* Pw = &Plds[wid][0];

  const half8 aq0 = *(const half8*)(Qh + l15 * HD + quad * 8);
  const half8 aq1 = *(const half8*)(Qh + l15 * HD + 32 + quad * 8);
  const half8 bk0 = *(const half8*)(Kh + l15 * HD + quad * 8);
  const half8 bk1 = *(const half8*)(Kh + l15 * HD + 32 + quad * 8);
  f32x4 s = (f32x4)0.0f;
  s = MFMA(aq0, bk0, s);
  s = MFMA(aq1, bk1, s);
  s = s * 0.125f;

  f32x4 mx = s;
#pragma unroll
  for (int off = 1; off < 16; off <<= 1) {
    mx.x = fmaxf(mx.x, __shfl_xor(mx.x, off, 16));
    mx.y = fmaxf(mx.y, __shfl_xor(mx.y, off, 16));
    mx.z = fmaxf(mx.z, __shfl_xor(mx.z, off, 16));
    mx.w = fmaxf(mx.w, __shfl_xor(mx.w, off, 16));
  }
  f32x4 e;
  e.x = __expf(s.x - mx.x); e.y = __expf(s.y - mx.y);
  e.z = __expf(s.z - mx.z); e.w = __expf(s.w - mx.w);
  f32x4 sm = e;
#pragma unroll
  for (int off = 1; off < 16; off <<= 1) {
    sm.x += __shfl_xor(sm.x, off, 16);
    sm.y += __shfl_xor(sm.y, off, 16);
    sm.z += __shfl_xor(sm.z, off, 16);
    sm.w += __shfl_xor(sm.w, off, 16);
  }

  Pw[(quad * 4 + 0) * 32 + l15] = (_Float16)e.x;
  Pw[(quad * 4 + 1) * 32 + l15] = (_Float16)e.y;
  Pw[(quad * 4 + 2) * 32 + l15] = (_Float16)e.z;
  Pw[(quad * 4 + 3) * 32 + l15] = (_Float16)e.w;
  {  // zero-pad K dim 16..31
    half4h z4;
    z4.x = z4.y = z4.z = z4.w = (_Float16)0.0f;
    *(half4h*)(Pw + l15 * 32 + 16 + quad * 4) = z4;
  }
  wave_fence_lds();

  const half8 ap = *(const half8*)(Pw + l15 * 32 + quad * 8);
  half8 h8z;
#pragma unroll
  for (int z = 0; z < 8; ++z) h8z[z] = (_Float16)0.0f;

  f32x4 o[4];
#pragma unroll
  for (int tj = 0; tj < 4; ++tj) {
    const int d = tj * 16 + l15;
    half8 bv = h8z;
    if (quad < 2)  // keys 0..15 real; 16..31 zero (stay in bounds)
      bv = *(const half8*)(Vh + (size_t)d * Nn + quad * 8);
    o[tj] = MFMA(ap, bv, o[tj]);
  }
  const float invs[4] = {1.0f / sm.x, 1.0f / sm.y, 1.0f / sm.z, 1.0f / sm.w};
#pragma unroll
  for (int tj = 0; tj < 4; ++tj) {
    const int d = tj * 16 + l15;
#pragma unroll
    for (int r = 0; r < 4; ++r) {
      const int q = quad * 4 + r;
      Wbuf[(size_t)(b * Nn + n0 + q) * Dd + (6 + hh) * HD + d] =
          (_Float16)(o[tj][r] * invs[r]);
    }
  }
}

// ---------------------------------------------------------------- launcher
extern "C" void kernel_launch(void* const* d_in, const int* in_sizes, int n_in,
                              void* d_out, int out_size, void* d_ws, size_t ws_size,
                              hipStream_t stream) {
  const float* x = (const float*)d_in[0];       // 8*16*196*768
  const float* w_qkv = (const float*)d_in[1];   // 2304*768
  const float* w_proj = (const float*)d_in[2];  // 768*768
  const float* b_proj = (const float*)d_in[3];  // 768
  float* out = (float*)d_out;

  // ws layout (fp16 elems). Xh region is reused as Wbuf after gemm_qkv.
  _Float16* Xh = (_Float16*)d_ws;    // 19267584 elems (38.5 MB)
  _Float16* Qb = Xh + 19267584;      // (B,H,N,hd)
  _Float16* Kb = Qb + 19267584;
  _Float16* Vt = Kb + 19267584;      // (B,H,hd,N)  V transposed
  _Float16* Wqh = Vt + 19267584;     // 1769472
  _Float16* Wph = Wqh + 1769472;     // 589824
  // total = 158,859,264 bytes

  cvt_f32_f16<<<18816, 256, 0, stream>>>(x, Xh, 4816896);
  cvt_f32_f16<<<1728, 256, 0, stream>>>(w_qkv, Wqh, 442368);
  cvt_f32_f16<<<576, 256, 0, stream>>>(w_proj, Wph, 147456);
  gemm_qkv<<<dim3(18, 196), 256, 0, stream>>>(Xh, Wqh, Qb, Kb, Vt);
  attn_spatial<<<768, 256, 0, stream>>>(Qb, Kb, Vt, Xh);
  attn_temporal<<<2352, 256, 0, stream>>>(Qb, Kb, Vt, Xh);
  gemm_proj<<<dim3(6, 196), 256, 0, stream>>>(Xh, Wph, b_proj, out);
}

// Round 2
// 389.061 us; speedup vs baseline: 1.0859x; 1.0859x over previous
//
#include <hip/hip_runtime.h>

#define DEV __device__ __forceinline__

typedef _Float16 half8  __attribute__((ext_vector_type(8)));
typedef _Float16 half4h __attribute__((ext_vector_type(4)));
typedef float    f32x4  __attribute__((ext_vector_type(4)));

static constexpr int Bb = 8;
static constexpr int Ff = 16;
static constexpr int Pp = 196;
static constexpr int Dd = 768;
static constexpr int Hh = 12;
static constexpr int HD = 64;
static constexpr int Nn = 3136;    // F*P tokens per batch
static constexpr int NC = 392;     // Nn/8 token chunks per batch

#define MFMA(a, b, c) __builtin_amdgcn_mfma_f32_16x16x32_f16(a, b, c, 0, 0, 0)

DEV void gll16(const _Float16* g, _Float16* l) {
  __builtin_amdgcn_global_load_lds(
      (__attribute__((address_space(1))) void*)(g),
      (__attribute__((address_space(3))) void*)(l), 16, 0, 0);
}

DEV void wave_fence_lds() {
  __builtin_amdgcn_sched_barrier(0);
  __builtin_amdgcn_s_waitcnt(0);
  __builtin_amdgcn_sched_barrier(0);
}

// ---------------------------------------------------------------- convert
__global__ __launch_bounds__(256) void cvt_f32_f16(const float* __restrict__ s,
                                                   _Float16* __restrict__ d,
                                                   int n4) {
  int i = blockIdx.x * 256 + threadIdx.x;
  if (i >= n4) return;
  f32x4 v = ((const f32x4*)s)[i];
  half4h h;
  h.x = (_Float16)v.x; h.y = (_Float16)v.y;
  h.z = (_Float16)v.z; h.w = (_Float16)v.w;
  ((half4h*)d)[i] = h;
}

// ---------------------------------------------------------------- QKV GEMM
// C[token][e] = sum_d X[token][d]*W[e][d]; M=25088,N=2304,K=768. 128x128 tile.
// Staging is XOR-chunk-swizzled (kills 8-way ds_read_b128 conflicts).
// Outputs: Q8/K8 (b,h,dc,n,8)  V8 (b,h,n/8,d,8) for coalesced attention loads.
__global__ __launch_bounds__(256) void gemm_qkv(const _Float16* __restrict__ X,
                                                const _Float16* __restrict__ W,
                                                _Float16* __restrict__ Q8,
                                                _Float16* __restrict__ K8,
                                                _Float16* __restrict__ V8) {
  __shared__ __align__(16) _Float16 smem[128 * 132];  // 33792 B (stage + C-tile)
  _Float16* As = smem;             // [128][32] swizzled
  _Float16* Bs = smem + 128 * 32;
  const int tid = threadIdx.x;
  const int lane = tid & 63, wid = tid >> 6;
  const int l15 = lane & 15, quad = lane >> 4;
  const int row0 = blockIdx.y * 128;
  const int e0 = blockIdx.x * 128;
  const int wm = (wid >> 1) * 64, wn = (wid & 1) * 64;

  const _Float16* Ag = X + (size_t)row0 * Dd;
  const _Float16* Bg = W + (size_t)e0 * Dd;

  f32x4 acc[4][4];
#pragma unroll
  for (int i = 0; i < 4; ++i)
#pragma unroll
    for (int j = 0; j < 4; ++j) acc[i][j] = (f32x4)0.0f;

  // staging: slot c holds row r=c>>2, stored-chunk cs=c&3 = global chunk cs^sw(r)
  const int c0 = tid, c1 = tid + 256;
  const int r0s = c0 >> 2, o0 = ((c0 & 3) ^ ((r0s >> 1) & 3)) * 8;
  const int r1s = c1 >> 2, o1 = ((c1 & 3) ^ ((r1s >> 1) & 3)) * 8;
  const int csel = ((quad ^ ((l15 >> 1) & 3))) * 8;  // fragment-read chunk

  for (int kt = 0; kt < 24; ++kt) {
    const int k0 = kt * 32;
    __syncthreads();
    gll16(Ag + (size_t)r0s * Dd + k0 + o0, As + c0 * 8);
    gll16(Bg + (size_t)r0s * Dd + k0 + o0, Bs + c0 * 8);
    gll16(Ag + (size_t)r1s * Dd + k0 + o1, As + c1 * 8);
    gll16(Bg + (size_t)r1s * Dd + k0 + o1, Bs + c1 * 8);
    __syncthreads();
    half8 af[4], bf[4];
#pragma unroll
    for (int t = 0; t < 4; ++t) {
      af[t] = *(const half8*)(As + (wm + t * 16 + l15) * 32 + csel);
      bf[t] = *(const half8*)(Bs + (wn + t * 16 + l15) * 32 + csel);
    }
#pragma unroll
    for (int i = 0; i < 4; ++i)
#pragma unroll
      for (int j = 0; j < 4; ++j) acc[i][j] = MFMA(af[i], bf[j], acc[i][j]);
  }

  __syncthreads();
  const int tsel = e0 / Dd;  // 0=Q,1=K,2=V
  if (tsel == 2) {
    // transpose to LDS Ct[e_local][tok], stride 132
#pragma unroll
    for (int i = 0; i < 4; ++i)
#pragma unroll
      for (int j = 0; j < 4; ++j) {
        const int m = wm + i * 16 + quad * 4;
        const int n = wn + j * 16 + l15;
        half4h hv;
        hv.x = (_Float16)acc[i][j].x; hv.y = (_Float16)acc[i][j].y;
        hv.z = (_Float16)acc[i][j].z; hv.w = (_Float16)acc[i][j].w;
        *(half4h*)(smem + n * 132 + m) = hv;
      }
    __syncthreads();
    for (int c = tid; c < 2048; c += 256) {
      const int ncl = c >> 7, el = c & 127;  // 128 consecutive el -> coalesced
      const int e = e0 + el;
      const int h = (e >> 6) % Hh, d = e & 63;
      const int r = row0 + ncl * 8;
      const int b = r / Nn, n = r % Nn;
      const half4h lo = *(const half4h*)(smem + el * 132 + ncl * 8);
      const half4h hi = *(const half4h*)(smem + el * 132 + ncl * 8 + 4);
      half8 v;
#pragma unroll
      for (int z = 0; z < 4; ++z) { v[z] = lo[z]; v[4 + z] = hi[z]; }
      *(half8*)(V8 + (((size_t)(b * Hh + h) * NC + (n >> 3)) * 64 + d) * 8) = v;
    }
  } else {
    _Float16* Ob = (tsel == 0) ? Q8 : K8;
#pragma unroll
    for (int i = 0; i < 4; ++i)
#pragma unroll
      for (int j = 0; j < 4; ++j) {
        const int n = wn + j * 16 + l15;
#pragma unroll
        for (int r = 0; r < 4; ++r) {
          const int m = wm + i * 16 + quad * 4 + r;
          smem[m * 132 + n] = (_Float16)acc[i][j][r];
        }
      }
    __syncthreads();
    for (int c = tid; c < 2048; c += 256) {
      const int ec = c >> 7, m = c & 127;  // 128 consecutive m -> coalesced
      const int r = row0 + m;
      const int b = r / Nn, n = r % Nn;
      const int e = e0 + ec * 8;
      const int h = (e >> 6) % Hh, dc = (e >> 3) & 7;
      const half4h lo = *(const half4h*)(smem + m * 132 + ec * 8);
      const half4h hi = *(const half4h*)(smem + m * 132 + ec * 8 + 4);
      half8 v;
#pragma unroll
      for (int z = 0; z < 4; ++z) { v[z] = lo[z]; v[4 + z] = hi[z]; }
      *(half8*)(Ob + (((size_t)(b * Hh + h) * 8 + dc) * Nn + n) * 8) = v;
    }
  }
}

// ---------------------------------------------------------------- proj GEMM
__global__ __launch_bounds__(256) void gemm_proj(const _Float16* __restrict__ Wbuf,
                                                 const _Float16* __restrict__ Wp,
                                                 const float* __restrict__ bias,
                                                 float* __restrict__ Out) {
  __shared__ __align__(16) _Float16 smem[128 * 64];
  _Float16* As = smem;
  _Float16* Bs = smem + 128 * 32;
  const int tid = threadIdx.x;
  const int lane = tid & 63, wid = tid >> 6;
  const int l15 = lane & 15, quad = lane >> 4;
  const int row0 = blockIdx.y * 128;
  const int e0 = blockIdx.x * 128;
  const int wm = (wid >> 1) * 64, wn = (wid & 1) * 64;

  const _Float16* Ag = Wbuf + (size_t)row0 * Dd;
  const _Float16* Bg = Wp + (size_t)e0 * Dd;

  f32x4 acc[4][4];
#pragma unroll
  for (int i = 0; i < 4; ++i)
#pragma unroll
    for (int j = 0; j < 4; ++j) acc[i][j] = (f32x4)0.0f;

  const int c0 = tid, c1 = tid + 256;
  const int r0s = c0 >> 2, o0 = ((c0 & 3) ^ ((r0s >> 1) & 3)) * 8;
  const int r1s = c1 >> 2, o1 = ((c1 & 3) ^ ((r1s >> 1) & 3)) * 8;
  const int csel = ((quad ^ ((l15 >> 1) & 3))) * 8;

  for (int kt = 0; kt < 24; ++kt) {
    const int k0 = kt * 32;
    __syncthreads();
    gll16(Ag + (size_t)r0s * Dd + k0 + o0, As + c0 * 8);
    gll16(Bg + (size_t)r0s * Dd + k0 + o0, Bs + c0 * 8);
    gll16(Ag + (size_t)r1s * Dd + k0 + o1, As + c1 * 8);
    gll16(Bg + (size_t)r1s * Dd + k0 + o1, Bs + c1 * 8);
    __syncthreads();
    half8 af[4], bf[4];
#pragma unroll
    for (int t = 0; t < 4; ++t) {
      af[t] = *(const half8*)(As + (wm + t * 16 + l15) * 32 + csel);
      bf[t] = *(const half8*)(Bs + (wn + t * 16 + l15) * 32 + csel);
    }
#pragma unroll
    for (int i = 0; i < 4; ++i)
#pragma unroll
      for (int j = 0; j < 4; ++j) acc[i][j] = MFMA(af[i], bf[j], acc[i][j]);
  }

#pragma unroll
  for (int j = 0; j < 4; ++j) {
    const int e = e0 + wn + j * 16 + l15;
    const float bj = bias[e];
#pragma unroll
    for (int i = 0; i < 4; ++i) {
      const int rb = row0 + wm + i * 16 + quad * 4;
#pragma unroll
      for (int r = 0; r < 4; ++r)
        Out[(size_t)(rb + r) * Dd + e] = acc[i][j][r] + bj;
    }
  }
}

// ------------------------------------------------------------ spatial attn
// Block = (b,f,h<6). V staged in LDS (coalesced from V8); Q/K direct from
// Q8/K8 (lane-consecutive-token, coalesced). P LDS chunk-XOR-swizzled.
__global__ __launch_bounds__(256) void attn_spatial(const _Float16* __restrict__ Q8,
                                                    const _Float16* __restrict__ K8,
                                                    const _Float16* __restrict__ V8,
                                                    _Float16* __restrict__ Wbuf) {
  __shared__ __align__(16) _Float16 Vs[64 * 216];       // 27648 B
  __shared__ __align__(16) _Float16 Plds[4][16 * 224];  // 28672 B
  const int tid = threadIdx.x;
  const int lane = tid & 63, wid = tid >> 6;
  const int l15 = lane & 15, quad = lane >> 4;
  const int gid = blockIdx.x;
  const int h = gid % 6, f = (gid / 6) % Ff, b = gid / 96;
  const size_t bh = (size_t)b * Hh + h;
  const int g0 = f * Pp;
  const int off = g0 & 7;   // 0 or 4
  const int nc0 = g0 >> 3;
  const _Float16* Qp = Q8 + bh * 8 * (size_t)Nn * 8;
  const _Float16* Kp = K8 + bh * 8 * (size_t)Nn * 8;

  // stage V: 26 chunks x 64 d; LDS key index = 8 + actual_key
  for (int c = tid; c < 26 * 64; c += 256) {
    const int d = c & 63, ncl = c >> 6;
    const half8 v = *(const half8*)(V8 + ((bh * NC + nc0 + ncl) * 64 + d) * 8);
    _Float16* dst = Vs + d * 216 + (8 - off) + ncl * 8;
    half4h lo, hi;
#pragma unroll
    for (int z = 0; z < 4; ++z) { lo[z] = v[z]; hi[z] = v[4 + z]; }
    *(half4h*)dst = lo;
    *(half4h*)(dst + 4) = hi;
  }
  _Float16* Pw = &Plds[wid][0];
  const int swzA = (l15 >> 1) & 3;
  {  // zero logical col-chunks 26,27 (cols 208..223), all 16 rows
    if (quad < 2) {
      const int row = l15;
      const int st = (26 + quad) ^ ((row >> 1) & 3);
      half8 z8;
#pragma unroll
      for (int z = 0; z < 8; ++z) z8[z] = (_Float16)0.0f;
      *(half8*)(Pw + row * 224 + st * 8) = z8;
    }
  }
  __syncthreads();

  half8 h8z;
#pragma unroll
  for (int z = 0; z < 8; ++z) h8z[z] = (_Float16)0.0f;

  for (int it = 0; it < 4; ++it) {
    const int qi = wid + it * 4;
    if (qi > 12) continue;
    const int qr = qi * 16 + l15;
    const int qc = qr < 195 ? qr : 195;
    const half8 aq0 = *(const half8*)(Qp + ((size_t)quad * Nn + g0 + qc) * 8);
    const half8 aq1 = *(const half8*)(Qp + ((size_t)(quad + 4) * Nn + g0 + qc) * 8);

    f32x4 s[13];
#pragma unroll
    for (int kt = 0; kt < 13; ++kt) {
      const int krr = kt * 16 + l15;
      const int kc = krr < 195 ? krr : 195;
      const half8 bk0 = *(const half8*)(Kp + ((size_t)quad * Nn + g0 + kc) * 8);
      const half8 bk1 = *(const half8*)(Kp + ((size_t)(quad + 4) * Nn + g0 + kc) * 8);
      f32x4 t = (f32x4)0.0f;
      t = MFMA(aq0, bk0, t);
      t = MFMA(aq1, bk1, t);
      s[kt] = t * 0.125f;
    }
    if (l15 >= 4) s[12] = (f32x4)(-1e30f);  // mask keys 196..207

    f32x4 mx = s[0];
#pragma unroll
    for (int kt = 1; kt < 13; ++kt)
#pragma unroll
      for (int r = 0; r < 4; ++r) mx[r] = fmaxf(mx[r], s[kt][r]);
#pragma unroll
    for (int o1 = 1; o1 < 16; o1 <<= 1)
#pragma unroll
      for (int r = 0; r < 4; ++r) mx[r] = fmaxf(mx[r], __shfl_xor(mx[r], o1, 16));

    f32x4 sm = (f32x4)0.0f;
#pragma unroll
    for (int kt = 0; kt < 13; ++kt) {
      f32x4 e;
#pragma unroll
      for (int r = 0; r < 4; ++r) e[r] = __expf(s[kt][r] - mx[r]);
      sm += e;
      const int cc = kt * 2 + (l15 >> 3);  // logical 8-col chunk
      const int jc = l15 & 7;
#pragma unroll
      for (int r = 0; r < 4; ++r) {
        const int row = quad * 4 + r;
        const int st = cc ^ ((row >> 1) & 3);
        Pw[row * 224 + st * 8 + jc] = (_Float16)e[r];
      }
    }
#pragma unroll
    for (int o1 = 1; o1 < 16; o1 <<= 1)
#pragma unroll
      for (int r = 0; r < 4; ++r) sm[r] += __shfl_xor(sm[r], o1, 16);
    wave_fence_lds();

    f32x4 o[4];
#pragma unroll
    for (int tj = 0; tj < 4; ++tj) o[tj] = (f32x4)0.0f;
#pragma unroll
    for (int ks = 0; ks < 7; ++ks) {
      const half8 ap = *(const half8*)(Pw + l15 * 224 + (ks * 4 + (quad ^ swzA)) * 8);
      const int k0 = ks * 32 + quad * 8;
#pragma unroll
      for (int tj = 0; tj < 4; ++tj) {
        const int d = tj * 16 + l15;
        half8 bv = h8z;
        if (k0 < 196) bv = *(const half8*)(Vs + d * 216 + 8 + k0);
        o[tj] = MFMA(ap, bv, o[tj]);
      }
    }
    const float invs[4] = {1.0f / sm[0], 1.0f / sm[1], 1.0f / sm[2], 1.0f / sm[3]};
#pragma unroll
    for (int tj = 0; tj < 4; ++tj) {
      const int d = tj * 16 + l15;
#pragma unroll
      for (int r = 0; r < 4; ++r) {
        const int q = qi * 16 + quad * 4 + r;
        if (q < 196)
          Wbuf[(size_t)(b * Nn + g0 + q) * Dd + h * HD + d] =
              (_Float16)(o[tj][r] * invs[r]);
      }
    }
    wave_fence_lds();  // WAR: PV reads done before next tile's P writes
  }
}

// ----------------------------------------------------------- temporal attn
// 16 consecutive tokens within (b, head 6..11) per wave; coalesced Q8/K8/V8.
__global__ __launch_bounds__(256) void attn_temporal(const _Float16* __restrict__ Q8,
                                                     const _Float16* __restrict__ K8,
                                                     const _Float16* __restrict__ V8,
                                                     _Float16* __restrict__ Wbuf) {
  __shared__ __align__(16) _Float16 Plds[4][16 * 36];  // stride-36 pad
  const int tid = threadIdx.x;
  const int lane = tid & 63, wid = tid >> 6;
  const int l15 = lane & 15, quad = lane >> 4;
  const int p = blockIdx.x * 4 + wid;  // [0, 9408)
  const int J0 = p << 4;
  const int b = J0 / 18816;            // H2*N
  const int rem = J0 % 18816;
  const int hh = rem / Nn;
  const int n0 = rem % Nn;             // 16-aligned
  const size_t bh = (size_t)b * Hh + 6 + hh;
  const _Float16* Qp = Q8 + bh * 8 * (size_t)Nn * 8;
  const _Float16* Kp = K8 + bh * 8 * (size_t)Nn * 8;
  _Float16* Pw = &Plds[wid][0];

  const half8 aq0 = *(const half8*)(Qp + ((size_t)quad * Nn + n0 + l15) * 8);
  const half8 aq1 = *(const half8*)(Qp + ((size_t)(quad + 4) * Nn + n0 + l15) * 8);
  const half8 bk0 = *(const half8*)(Kp + ((size_t)quad * Nn + n0 + l15) * 8);
  const half8 bk1 = *(const half8*)(Kp + ((size_t)(quad + 4) * Nn + n0 + l15) * 8);
  f32x4 s = (f32x4)0.0f;
  s = MFMA(aq0, bk0, s);
  s = MFMA(aq1, bk1, s);
  s = s * 0.125f;

  f32x4 mx = s;
#pragma unroll
  for (int o1 = 1; o1 < 16; o1 <<= 1)
#pragma unroll
    for (int r = 0; r < 4; ++r) mx[r] = fmaxf(mx[r], __shfl_xor(mx[r], o1, 16));
  f32x4 e;
#pragma unroll
  for (int r = 0; r < 4; ++r) e[r] = __expf(s[r] - mx[r]);
  f32x4 sm = e;
#pragma unroll
  for (int o1 = 1; o1 < 16; o1 <<= 1)
#pragma unroll
    for (int r = 0; r < 4; ++r) sm[r] += __shfl_xor(sm[r], o1, 16);

#pragma unroll
  for (int r = 0; r < 4; ++r) Pw[(quad * 4 + r) * 36 + l15] = (_Float16)e[r];
  {  // zero cols 16..31
    half4h z4;
    z4.x = z4.y = z4.z = z4.w = (_Float16)0.0f;
    *(half4h*)(Pw + l15 * 36 + 16 + quad * 4) = z4;
  }
  wave_fence_lds();

  const half8 ap = *(const half8*)(Pw + l15 * 36 + quad * 8);
  half8 h8z;
#pragma unroll
  for (int z = 0; z < 8; ++z) h8z[z] = (_Float16)0.0f;

  f32x4 o[4];
#pragma unroll
  for (int tj = 0; tj < 4; ++tj) {
    const int d = tj * 16 + l15;
    half8 bv = h8z;
    if (quad < 2)
      bv = *(const half8*)(V8 + ((bh * NC + (n0 >> 3) + quad) * 64 + d) * 8);
    o[tj] = (f32x4)0.0f;
    o[tj] = MFMA(ap, bv, o[tj]);
  }
  const float invs[4] = {1.0f / sm[0], 1.0f / sm[1], 1.0f / sm[2], 1.0f / sm[3]};
#pragma unroll
  for (int tj = 0; tj < 4; ++tj) {
    const int d = tj * 16 + l15;
#pragma unroll
    for (int r = 0; r < 4; ++r) {
      const int q = quad * 4 + r;
      Wbuf[(size_t)(b * Nn + n0 + q) * Dd + (6 + hh) * HD + d] =
          (_Float16)(o[tj][r] * invs[r]);
    }
  }
}

// ---------------------------------------------------------------- launcher
extern "C" void kernel_launch(void* const* d_in, const int* in_sizes, int n_in,
                              void* d_out, int out_size, void* d_ws, size_t ws_size,
                              hipStream_t stream) {
  const float* x = (const float*)d_in[0];
  const float* w_qkv = (const float*)d_in[1];
  const float* w_proj = (const float*)d_in[2];
  const float* b_proj = (const float*)d_in[3];
  float* out = (float*)d_out;

  _Float16* Xh = (_Float16*)d_ws;    // 19267584 elems; reused as Wbuf
  _Float16* Q8 = Xh + 19267584;      // (b,h,dc,n,8)
  _Float16* K8 = Q8 + 19267584;
  _Float16* V8 = K8 + 19267584;      // (b,h,n/8,d,8)
  _Float16* Wqh = V8 + 19267584;     // 1769472
  _Float16* Wph = Wqh + 1769472;     // 589824

  cvt_f32_f16<<<18816, 256, 0, stream>>>(x, Xh, 4816896);
  cvt_f32_f16<<<1728, 256, 0, stream>>>(w_qkv, Wqh, 442368);
  cvt_f32_f16<<<576, 256, 0, stream>>>(w_proj, Wph, 147456);
  gemm_qkv<<<dim3(18, 196), 256, 0, stream>>>(Xh, Wqh, Q8, K8, V8);
  attn_spatial<<<768, 256, 0, stream>>>(Q8, K8, V8, Xh);
  attn_temporal<<<2352, 256, 0, stream>>>(Q8, K8, V8, Xh);
  gemm_proj<<<dim3(6, 196), 256, 0, stream>>>(Xh, Wph, b_proj, out);
}

// Round 3
// 369.397 us; speedup vs baseline: 1.1437x; 1.0532x over previous
//
#include <hip/hip_runtime.h>

#define DEV __device__ __forceinline__

typedef _Float16 half8  __attribute__((ext_vector_type(8)));
typedef _Float16 half4h __attribute__((ext_vector_type(4)));
typedef float    f32x4  __attribute__((ext_vector_type(4)));

static constexpr int Bb = 8;
static constexpr int Ff = 16;
static constexpr int Pp = 196;
static constexpr int Dd = 768;
static constexpr int Hh = 12;
static constexpr int HD = 64;
static constexpr int Nn = 3136;    // F*P tokens per batch
static constexpr int NC = 392;     // Nn/8 token chunks per batch

#define MFMA(a, b, c) __builtin_amdgcn_mfma_f32_16x16x32_f16(a, b, c, 0, 0, 0)

DEV void gll16(const _Float16* g, _Float16* l) {
  __builtin_amdgcn_global_load_lds(
      (__attribute__((address_space(1))) void*)(g),
      (__attribute__((address_space(3))) void*)(l), 16, 0, 0);
}

// LDS-only fence: wait DS ops, compiler memory barrier. Does NOT drain vmcnt,
// so global loads stay in flight across it.
DEV void lds_fence() { asm volatile("s_waitcnt lgkmcnt(0)" ::: "memory"); }

// ---------------------------------------------------------------- convert
// One kernel for all three fp32->fp16 conversions (x, w_qkv, w_proj).
__global__ __launch_bounds__(256) void cvt_all(const float* __restrict__ x,
                                               const float* __restrict__ wq,
                                               const float* __restrict__ wp,
                                               _Float16* __restrict__ xh,
                                               _Float16* __restrict__ wqh,
                                               _Float16* __restrict__ wph) {
  const int NX = 4816896, NQ = 442368;  // in f32x4 units
  int i = blockIdx.x * 256 + threadIdx.x;
  const float* s;
  _Float16* d;
  int j;
  if (i < NX) { s = x; d = xh; j = i; }
  else if (i < NX + NQ) { s = wq; d = wqh; j = i - NX; }
  else { s = wp; d = wph; j = i - NX - NQ; }
  f32x4 v = ((const f32x4*)s)[j];
  half4h h;
  h.x = (_Float16)v.x; h.y = (_Float16)v.y;
  h.z = (_Float16)v.z; h.w = (_Float16)v.w;
  ((half4h*)d)[j] = h;
}

// ---------------------------------------------------------------- QKV GEMM
// (unchanged from R2 — 0 bank conflicts, m97-plateau structure)
__global__ __launch_bounds__(256) void gemm_qkv(const _Float16* __restrict__ X,
                                                const _Float16* __restrict__ W,
                                                _Float16* __restrict__ Q8,
                                                _Float16* __restrict__ K8,
                                                _Float16* __restrict__ V8) {
  __shared__ __align__(16) _Float16 smem[128 * 132];
  _Float16* As = smem;
  _Float16* Bs = smem + 128 * 32;
  const int tid = threadIdx.x;
  const int lane = tid & 63, wid = tid >> 6;
  const int l15 = lane & 15, quad = lane >> 4;
  const int row0 = blockIdx.y * 128;
  const int e0 = blockIdx.x * 128;
  const int wm = (wid >> 1) * 64, wn = (wid & 1) * 64;

  const _Float16* Ag = X + (size_t)row0 * Dd;
  const _Float16* Bg = W + (size_t)e0 * Dd;

  f32x4 acc[4][4];
#pragma unroll
  for (int i = 0; i < 4; ++i)
#pragma unroll
    for (int j = 0; j < 4; ++j) acc[i][j] = (f32x4)0.0f;

  const int c0 = tid, c1 = tid + 256;
  const int r0s = c0 >> 2, o0 = ((c0 & 3) ^ ((r0s >> 1) & 3)) * 8;
  const int r1s = c1 >> 2, o1 = ((c1 & 3) ^ ((r1s >> 1) & 3)) * 8;
  const int csel = ((quad ^ ((l15 >> 1) & 3))) * 8;

  for (int kt = 0; kt < 24; ++kt) {
    const int k0 = kt * 32;
    __syncthreads();
    gll16(Ag + (size_t)r0s * Dd + k0 + o0, As + c0 * 8);
    gll16(Bg + (size_t)r0s * Dd + k0 + o0, Bs + c0 * 8);
    gll16(Ag + (size_t)r1s * Dd + k0 + o1, As + c1 * 8);
    gll16(Bg + (size_t)r1s * Dd + k0 + o1, Bs + c1 * 8);
    __syncthreads();
    half8 af[4], bf[4];
#pragma unroll
    for (int t = 0; t < 4; ++t) {
      af[t] = *(const half8*)(As + (wm + t * 16 + l15) * 32 + csel);
      bf[t] = *(const half8*)(Bs + (wn + t * 16 + l15) * 32 + csel);
    }
#pragma unroll
    for (int i = 0; i < 4; ++i)
#pragma unroll
      for (int j = 0; j < 4; ++j) acc[i][j] = MFMA(af[i], bf[j], acc[i][j]);
  }

  __syncthreads();
  const int tsel = e0 / Dd;
  if (tsel == 2) {
#pragma unroll
    for (int i = 0; i < 4; ++i)
#pragma unroll
      for (int j = 0; j < 4; ++j) {
        const int m = wm + i * 16 + quad * 4;
        const int n = wn + j * 16 + l15;
        half4h hv;
        hv.x = (_Float16)acc[i][j].x; hv.y = (_Float16)acc[i][j].y;
        hv.z = (_Float16)acc[i][j].z; hv.w = (_Float16)acc[i][j].w;
        *(half4h*)(smem + n * 132 + m) = hv;
      }
    __syncthreads();
    for (int c = tid; c < 2048; c += 256) {
      const int ncl = c >> 7, el = c & 127;
      const int e = e0 + el;
      const int h = (e >> 6) % Hh, d = e & 63;
      const int r = row0 + ncl * 8;
      const int b = r / Nn, n = r % Nn;
      const half4h lo = *(const half4h*)(smem + el * 132 + ncl * 8);
      const half4h hi = *(const half4h*)(smem + el * 132 + ncl * 8 + 4);
      half8 v;
#pragma unroll
      for (int z = 0; z < 4; ++z) { v[z] = lo[z]; v[4 + z] = hi[z]; }
      *(half8*)(V8 + (((size_t)(b * Hh + h) * NC + (n >> 3)) * 64 + d) * 8) = v;
    }
  } else {
    _Float16* Ob = (tsel == 0) ? Q8 : K8;
#pragma unroll
    for (int i = 0; i < 4; ++i)
#pragma unroll
      for (int j = 0; j < 4; ++j) {
        const int n = wn + j * 16 + l15;
#pragma unroll
        for (int r = 0; r < 4; ++r) {
          const int m = wm + i * 16 + quad * 4 + r;
          smem[m * 132 + n] = (_Float16)acc[i][j][r];
        }
      }
    __syncthreads();
    for (int c = tid; c < 2048; c += 256) {
      const int ec = c >> 7, m = c & 127;
      const int r = row0 + m;
      const int b = r / Nn, n = r % Nn;
      const int e = e0 + ec * 8;
      const int h = (e >> 6) % Hh, dc = (e >> 3) & 7;
      const half4h lo = *(const half4h*)(smem + m * 132 + ec * 8);
      const half4h hi = *(const half4h*)(smem + m * 132 + ec * 8 + 4);
      half8 v;
#pragma unroll
      for (int z = 0; z < 4; ++z) { v[z] = lo[z]; v[4 + z] = hi[z]; }
      *(half8*)(Ob + (((size_t)(b * Hh + h) * 8 + dc) * Nn + n) * 8) = v;
    }
  }
}

// ---------------------------------------------------------------- proj GEMM
__global__ __launch_bounds__(256) void gemm_proj(const _Float16* __restrict__ Wbuf,
                                                 const _Float16* __restrict__ Wp,
                                                 const float* __restrict__ bias,
                                                 float* __restrict__ Out) {
  __shared__ __align__(16) _Float16 smem[128 * 64];
  _Float16* As = smem;
  _Float16* Bs = smem + 128 * 32;
  const int tid = threadIdx.x;
  const int lane = tid & 63, wid = tid >> 6;
  const int l15 = lane & 15, quad = lane >> 4;
  const int row0 = blockIdx.y * 128;
  const int e0 = blockIdx.x * 128;
  const int wm = (wid >> 1) * 64, wn = (wid & 1) * 64;

  const _Float16* Ag = Wbuf + (size_t)row0 * Dd;
  const _Float16* Bg = Wp + (size_t)e0 * Dd;

  f32x4 acc[4][4];
#pragma unroll
  for (int i = 0; i < 4; ++i)
#pragma unroll
    for (int j = 0; j < 4; ++j) acc[i][j] = (f32x4)0.0f;

  const int c0 = tid, c1 = tid + 256;
  const int r0s = c0 >> 2, o0 = ((c0 & 3) ^ ((r0s >> 1) & 3)) * 8;
  const int r1s = c1 >> 2, o1 = ((c1 & 3) ^ ((r1s >> 1) & 3)) * 8;
  const int csel = ((quad ^ ((l15 >> 1) & 3))) * 8;

  for (int kt = 0; kt < 24; ++kt) {
    const int k0 = kt * 32;
    __syncthreads();
    gll16(Ag + (size_t)r0s * Dd + k0 + o0, As + c0 * 8);
    gll16(Bg + (size_t)r0s * Dd + k0 + o0, Bs + c0 * 8);
    gll16(Ag + (size_t)r1s * Dd + k0 + o1, As + c1 * 8);
    gll16(Bg + (size_t)r1s * Dd + k0 + o1, Bs + c1 * 8);
    __syncthreads();
    half8 af[4], bf[4];
#pragma unroll
    for (int t = 0; t < 4; ++t) {
      af[t] = *(const half8*)(As + (wm + t * 16 + l15) * 32 + csel);
      bf[t] = *(const half8*)(Bs + (wn + t * 16 + l15) * 32 + csel);
    }
#pragma unroll
    for (int i = 0; i < 4; ++i)
#pragma unroll
      for (int j = 0; j < 4; ++j) acc[i][j] = MFMA(af[i], bf[j], acc[i][j]);
  }

#pragma unroll
  for (int j = 0; j < 4; ++j) {
    const int e = e0 + wn + j * 16 + l15;
    const float bj = bias[e];
#pragma unroll
    for (int i = 0; i < 4; ++i) {
      const int rb = row0 + wm + i * 16 + quad * 4;
#pragma unroll
      for (int r = 0; r < 4; ++r)
        Out[(size_t)(rb + r) * Dd + e] = acc[i][j][r] + bj;
    }
  }
}

// ------------------------------------------------------------ spatial attn
// Transposed scheme: St = K·Q^T (rows=keys -> softmax sum = 2 shuffles, no
// max pass), P^T lands row=q in LDS for PV's B-operand, V is the A-operand
// so the output is O^T with 4-consecutive-d rows -> packed 8B stores.
__global__ __launch_bounds__(256) void attn_spatial(const _Float16* __restrict__ Q8,
                                                    const _Float16* __restrict__ K8,
                                                    const _Float16* __restrict__ V8,
                                                    _Float16* __restrict__ Wbuf) {
  __shared__ __align__(16) _Float16 Vs[64 * 216];       // 27648 B
  __shared__ __align__(16) _Float16 Plds[4][16 * 232];  // 29696 B
  const int tid = threadIdx.x;
  const int lane = tid & 63, wid = tid >> 6;
  const int l15 = lane & 15, quad = lane >> 4;
  const int gid = blockIdx.x;
  const int h = gid % 6, f = (gid / 6) % Ff, b = gid / 96;
  const size_t bh = (size_t)b * Hh + h;
  const int g0 = f * Pp;
  const int off = g0 & 7;
  const int nc0 = g0 >> 3;
  const _Float16* Qp = Q8 + bh * 8 * (size_t)Nn * 8;
  const _Float16* Kp = K8 + bh * 8 * (size_t)Nn * 8;

  // stage V: Vs[d][8+key], keys -off..207-off of this (b,f)
  for (int c = tid; c < 26 * 64; c += 256) {
    const int d = c & 63, ncl = c >> 6;
    const half8 v = *(const half8*)(V8 + ((bh * NC + nc0 + ncl) * 64 + d) * 8);
    _Float16* dst = Vs + d * 216 + (8 - off) + ncl * 8;
    half4h lo, hi;
#pragma unroll
    for (int z = 0; z < 4; ++z) { lo[z] = v[z]; hi[z] = v[4 + z]; }
    *(half4h*)dst = lo;
    *(half4h*)(dst + 4) = hi;
  }
  _Float16* Pw = &Plds[wid][0];
  if (quad < 3) {  // zero P cols 208..231 (PV reads k up to 223)
    half8 z8;
#pragma unroll
    for (int z = 0; z < 8; ++z) z8[z] = (_Float16)0.0f;
    *(half8*)(Pw + l15 * 232 + 208 + quad * 8) = z8;
  }
  __syncthreads();

  half8 h8z;
#pragma unroll
  for (int z = 0; z < 8; ++z) h8z[z] = (_Float16)0.0f;

  for (int it = 0; it < 4; ++it) {
    const int qi = wid + it * 4;
    if (qi > 12) continue;
    const int qr = qi * 16 + l15;
    const int qtok = g0 + (qr < 195 ? qr : 195);
    // B-operand: Q[n=q][k=d]
    const half8 bq0 = *(const half8*)(Qp + ((size_t)quad * Nn + qtok) * 8);
    const half8 bq1 = *(const half8*)(Qp + ((size_t)(quad + 4) * Nn + qtok) * 8);

    f32x4 ex[13];
    float rs = 0.0f;
#pragma unroll
    for (int kt = 0; kt < 13; ++kt) {
      const int krr = kt * 16 + l15;
      const int ktok = g0 + (krr < 195 ? krr : 195);
      // A-operand: K[m=key][k=d]
      const half8 ak0 = *(const half8*)(Kp + ((size_t)quad * Nn + ktok) * 8);
      const half8 ak1 = *(const half8*)(Kp + ((size_t)(quad + 4) * Nn + ktok) * 8);
      f32x4 t = (f32x4)0.0f;
      t = MFMA(ak0, bq0, t);
      t = MFMA(ak1, bq1, t);
      f32x4 e;
#pragma unroll
      for (int r = 0; r < 4; ++r) e[r] = __expf(t[r] * 0.125f);
      if (kt == 12 && quad >= 1) e = (f32x4)0.0f;  // keys 196..207
      ex[kt] = e;
      rs += e[0] + e[1] + e[2] + e[3];
    }
    // write P^T rows: Pw[q=l15][k = kt*16 + quad*4 + r]
#pragma unroll
    for (int kt = 0; kt < 13; ++kt)
#pragma unroll
      for (int r = 0; r < 4; ++r)
        Pw[l15 * 232 + kt * 16 + quad * 4 + r] = (_Float16)ex[kt][r];
    rs += __shfl_xor(rs, 16);
    rs += __shfl_xor(rs, 32);  // every lane: sum over all keys for q=l15
    lds_fence();

    f32x4 acc[4];
#pragma unroll
    for (int mt = 0; mt < 4; ++mt) acc[mt] = (f32x4)0.0f;
#pragma unroll
    for (int c = 0; c < 7; ++c) {
      const half8 bp = *(const half8*)(Pw + l15 * 232 + c * 32 + quad * 8);
      const int k0 = c * 32 + quad * 8;
#pragma unroll
      for (int mt = 0; mt < 4; ++mt) {
        const int d = mt * 16 + l15;
        half8 av = h8z;
        if (k0 < 196) av = *(const half8*)(Vs + d * 216 + 8 + k0);
        acc[mt] = MFMA(av, bp, acc[mt]);  // O^T[d][q]
      }
    }
    const float inv = 1.0f / rs;
    if (qr < 196) {
      _Float16* base = Wbuf + (size_t)(b * Nn + g0 + qr) * Dd + h * HD;
#pragma unroll
      for (int mt = 0; mt < 4; ++mt) {
        half4h o;
#pragma unroll
        for (int r = 0; r < 4; ++r) o[r] = (_Float16)(acc[mt][r] * inv);
        *(half4h*)(base + mt * 16 + quad * 4) = o;
      }
    }
    __builtin_amdgcn_sched_barrier(0);
  }
}

// ----------------------------------------------------------- temporal attn
// Same transposed scheme; one wave per 16x16x64 problem (16 consecutive
// tokens within (b, head 6..11)).
__global__ __launch_bounds__(256) void attn_temporal(const _Float16* __restrict__ Q8,
                                                     const _Float16* __restrict__ K8,
                                                     const _Float16* __restrict__ V8,
                                                     _Float16* __restrict__ Wbuf) {
  __shared__ __align__(16) _Float16 Plds[4][16 * 40];
  const int tid = threadIdx.x;
  const int lane = tid & 63, wid = tid >> 6;
  const int l15 = lane & 15, quad = lane >> 4;
  const int p = blockIdx.x * 4 + wid;
  const int J0 = p << 4;
  const int b = J0 / 18816;  // H2*N
  const int rem = J0 % 18816;
  const int hh = rem / Nn;
  const int n0 = rem % Nn;   // 16-aligned
  const size_t bh = (size_t)b * Hh + 6 + hh;
  const _Float16* Qp = Q8 + bh * 8 * (size_t)Nn * 8;
  const _Float16* Kp = K8 + bh * 8 * (size_t)Nn * 8;
  _Float16* Pw = &Plds[wid][0];

  const int tok = n0 + l15;
  const half8 bq0 = *(const half8*)(Qp + ((size_t)quad * Nn + tok) * 8);
  const half8 bq1 = *(const half8*)(Qp + ((size_t)(quad + 4) * Nn + tok) * 8);
  const half8 ak0 = *(const half8*)(Kp + ((size_t)quad * Nn + tok) * 8);
  const half8 ak1 = *(const half8*)(Kp + ((size_t)(quad + 4) * Nn + tok) * 8);
  f32x4 t = (f32x4)0.0f;
  t = MFMA(ak0, bq0, t);  // St[k][q]
  t = MFMA(ak1, bq1, t);
  f32x4 e;
#pragma unroll
  for (int r = 0; r < 4; ++r) e[r] = __expf(t[r] * 0.125f);
  float rs = e[0] + e[1] + e[2] + e[3];
  rs += __shfl_xor(rs, 16);
  rs += __shfl_xor(rs, 32);

#pragma unroll
  for (int r = 0; r < 4; ++r) Pw[l15 * 40 + quad * 4 + r] = (_Float16)e[r];
  {
    half4h z4;
    z4.x = z4.y = z4.z = z4.w = (_Float16)0.0f;
    *(half4h*)(Pw + l15 * 40 + 16 + quad * 4) = z4;  // zero k=16..31
  }
  lds_fence();

  const half8 bp = *(const half8*)(Pw + l15 * 40 + quad * 8);  // B: P[q][k]
  half8 h8z;
#pragma unroll
  for (int z = 0; z < 8; ++z) h8z[z] = (_Float16)0.0f;

  const float inv = 1.0f / rs;
  _Float16* base = Wbuf + (size_t)(b * Nn + n0 + l15) * Dd + (6 + hh) * HD;
#pragma unroll
  for (int mt = 0; mt < 4; ++mt) {
    const int d = mt * 16 + l15;
    half8 av = h8z;
    if (quad < 2)
      av = *(const half8*)(V8 + ((bh * NC + (n0 >> 3) + quad) * 64 + d) * 8);
    f32x4 acc = (f32x4)0.0f;
    acc = MFMA(av, bp, acc);  // O^T[d][q]
    half4h o;
#pragma unroll
    for (int r = 0; r < 4; ++r) o[r] = (_Float16)(acc[r] * inv);
    *(half4h*)(base + mt * 16 + quad * 4) = o;
  }
}

// ---------------------------------------------------------------- launcher
extern "C" void kernel_launch(void* const* d_in, const int* in_sizes, int n_in,
                              void* d_out, int out_size, void* d_ws, size_t ws_size,
                              hipStream_t stream) {
  const float* x = (const float*)d_in[0];
  const float* w_qkv = (const float*)d_in[1];
  const float* w_proj = (const float*)d_in[2];
  const float* b_proj = (const float*)d_in[3];
  float* out = (float*)d_out;

  _Float16* Xh = (_Float16*)d_ws;    // 19267584 elems; reused as Wbuf
  _Float16* Q8 = Xh + 19267584;      // (b,h,dc,n,8)
  _Float16* K8 = Q8 + 19267584;
  _Float16* V8 = K8 + 19267584;      // (b,h,n/8,d,8)
  _Float16* Wqh = V8 + 19267584;     // 1769472
  _Float16* Wph = Wqh + 1769472;     // 589824

  cvt_all<<<21120, 256, 0, stream>>>(x, w_qkv, w_proj, Xh, Wqh, Wph);
  gemm_qkv<<<dim3(18, 196), 256, 0, stream>>>(Xh, Wqh, Q8, K8, V8);
  attn_spatial<<<768, 256, 0, stream>>>(Q8, K8, V8, Xh);
  attn_temporal<<<2352, 256, 0, stream>>>(Q8, K8, V8, Xh);
  gemm_proj<<<dim3(6, 196), 256, 0, stream>>>(Xh, Wph, b_proj, out);
}